// Round 18
// baseline (22.383 us; speedup 1.0000x reference)
//
#include <hip/hip_runtime.h>

#define NSTROKES 64
#define NSAMP    50
#define CANVAS   512
#define HW       (CANVAS * CANVAS)
#define TPB      1024                  // 512 px x 2 stroke-groups, 16 waves
#define SPW      (NSTROKES / 16)       // 4 strokes per wave (stage A)
#define LSTRIDE  64                    // float2 slots per stroke list
#define WS_NEED  ((size_t)NSTROKES * 64 * sizeof(float2))   // 32 KB sample table

// ---------------------------------------------------------------------------
// k1: compute the y-INDEPENDENT Bezier samples once (all 512 row-blocks were
// recomputing these identically). ws_pts[s*64 + j] = (px,py); slots j>=50
// get py=1e15 so the hot kernel's keep-test rejects them naturally.
// 32 KB -> L2-resident, broadcast-read by every block of k2.
// ---------------------------------------------------------------------------
__global__ __launch_bounds__(256) void sample_kernel(
    const float* __restrict__ strokes,   // (64,4,2)
    float2* __restrict__ ws_pts)         // [64][64]
{
    const int t = blockIdx.x * 256 + threadIdx.x;   // 4096
    const int s = t >> 6;
    const int j = t & 63;

    if (j >= NSAMP) {                    // pad: never kept
        ws_pts[t] = make_float2(1e15f, 1e15f);
        return;
    }

    float4 a = ((const float4*)strokes)[s * 2];       // p0x,p0y,p1x,p1y
    float4 b = ((const float4*)strokes)[s * 2 + 1];   // p2x,p2y,p3x,p3y
    const float S = (float)CANVAS;
    float c0x = a.x * S;
    float c1x = 3.0f * (a.z - a.x) * S;
    float c2x = 3.0f * (b.x - 2.0f * a.z + a.x) * S;
    float c3x = (b.z - 3.0f * b.x + 3.0f * a.z - a.x) * S;
    float c0y = a.y * S;
    float c1y = 3.0f * (a.w - a.y) * S;
    float c2y = 3.0f * (b.y - 2.0f * a.w + a.y) * S;
    float c3y = (b.w - 3.0f * b.y + 3.0f * a.w - a.y) * S;

    float tt = (float)j * (1.0f / (float)(NSAMP - 1));
    float px = fmaf(fmaf(fmaf(c3x, tt, c2x), tt, c1x), tt, c0x);
    float py = fmaf(fmaf(fmaf(c3y, tt, c2y), tt, c1y), tt, c0y);
    ws_pts[t] = make_float2(px, py);
}

// ---------------------------------------------------------------------------
// k2: r17 structure (one block per row; 512 px x 2 groups; dy^2 lists;
// single-barrier combine). stage A now just loads the shared sample table
// (one coalesced 8B read per (stroke,sample)) -- coeff+Horner work gone.
// stage B adds a far-pair skip: if every lane of the wave is > cut from
// every sample of BOTH popped strokes, their alphas are < 2e-9 -> skip the
// sigmoid+blend entirely (same bound as the compaction cut).
// ---------------------------------------------------------------------------
__global__ __launch_bounds__(TPB, 8) void raster_kernel(
    const float2* __restrict__ ws_pts,   // [64][64] samples
    const float* __restrict__ widths,    // (64,)
    const float* __restrict__ colors,    // (64,3)
    float* __restrict__ out)             // (1,3,512,512)
{
    __shared__ __align__(16) float2 slist[NSTROKES * LSTRIDE];  // 32 KB
    __shared__ float4 scull[NSTROKES];   // xmin-cut, xmax+cut, w, cnt
    __shared__ float4 scol [NSTROKES];   // r,g,b,pad
    __shared__ float4 xfer [512];        // dedicated combine buffer (8 KB)

    const int tid  = threadIdx.x;
    const int wave = tid >> 6;
    const int lane = tid & 63;
    const int px   = tid & 511;
    const int grp  = tid >> 9;           // 0: strokes 0-31, 1: strokes 32-63
    const int y    = blockIdx.x;
    const float fy = (float)y;

    // ---- stage A: load samples, band-test, ballot-compact (px, dy^2) lists
    #pragma unroll
    for (int i = 0; i < SPW; ++i) {
        const int s = wave * SPW + i;        // stroke id 0..63

        float2 q  = ws_pts[(s << 6) | lane]; // coalesced 8B/lane
        float  w  = widths[s];               // wave-uniform scalar load
        float cut = w + 10.0f;                // alpha <= sigmoid(-20) beyond

        float dy  = q.y - fy;
        bool keep = fabsf(dy) <= cut;         // pads have dy ~ 1e15 -> false
        unsigned long long mask = __ballot(keep);
        int idx = __popcll(mask & ((1ull << lane) - 1ull));
        if (keep) {
            slist[s * LSTRIDE + idx] = make_float2(q.x, dy * dy);
        } else if (lane >= NSAMP) {
            // lanes 50..63 never keep -> consecutive sentinel slots kc..kc+13
            slist[s * LSTRIDE + idx + (lane - NSAMP)] = make_float2(1e15f, 1e15f);
        }

        if (mask) {
            float vmn = keep ? q.x : 1e30f;
            float vmx = keep ? q.x : -1e30f;
            #pragma unroll
            for (int off = 32; off; off >>= 1) {
                vmn = fminf(vmn, __shfl_xor(vmn, off));
                vmx = fmaxf(vmx, __shfl_xor(vmx, off));
            }
            if (lane == 0) {
                scull[s] = make_float4(vmn - cut, vmx + cut, w,
                                       (float)__popcll(mask));
                scol [s] = make_float4(colors[3*s], colors[3*s+1],
                                       colors[3*s+2], 0.0f);
            }
        } else if (lane == 0) {
            scull[s] = make_float4(0.0f, 0.0f, w, 0.0f);   // cnt=0 -> culled
        }
    }
    __syncthreads();

    // ---- stage B: lane l tests stroke grp*32+(l&31); 32-bit live mask
    const float fx      = (float)px;
    const float span_lo = (float)((wave & 7) << 6);
    const float span_hi = span_lo + 63.0f;
    const int   sbase   = grp << 5;

    float4 cbl = scull[sbase + (lane & 31)];
    bool alive = (cbl.w > 0.0f) && (cbl.x <= span_hi) && (cbl.y >= span_lo);
    unsigned int live = (unsigned int)__ballot(alive);   // low 32 == high 32

    float A = 1.0f, br = 0.0f, bg = 0.0f, bb = 0.0f;

    while (live) {
        // pop up to TWO live strokes (ascending ids: composite order kept)
        const int s0 = sbase + (__ffs(live) - 1);
        live &= live - 1u;
        const bool has1 = (live != 0u);
        const int s1 = has1 ? (sbase + (__ffs(live) - 1)) : s0;
        if (has1) live &= live - 1u;

        // independent LDS reads issue back-to-back (2x MLP)
        float4 cb0  = scull[s0];
        float4 cb1  = scull[s1];
        float4 col0 = scol [s0];
        float4 col1 = scol [s1];
        const int   kc0 = (int)cb0.w;
        const int   kc1 = has1 ? (int)cb1.w : 0;
        const float w0  = cb0.z;
        const float w1  = cb1.z;

        float m0 = 1e30f, m1 = 1e30f;
        const float4* L0 = (const float4*)(slist + s0 * LSTRIDE);
        const float4* L1 = (const float4*)(slist + s1 * LSTRIDE);

        const int kmax = kc0 > kc1 ? kc0 : kc1;
        for (int j = 0; j < kmax; j += 4) {        // sentinel-padded to 4
            if (j < kc0) {                          // wave-uniform branch
                float4 q0 = L0[(j >> 1)];           // (px,dy2, px,dy2)
                float4 q1 = L0[(j >> 1) + 1];
                float d0 = fx - q0.x, d1 = fx - q0.z;
                float d2 = fx - q1.x, d3 = fx - q1.z;
                float a01 = fminf(fmaf(d0, d0, q0.y), fmaf(d1, d1, q0.w));
                float a23 = fminf(fmaf(d2, d2, q1.y), fmaf(d3, d3, q1.w));
                m0 = fminf(fminf(a01, a23), m0);
            }
            if (j < kc1) {                          // wave-uniform branch
                float4 q0 = L1[(j >> 1)];
                float4 q1 = L1[(j >> 1) + 1];
                float d0 = fx - q0.x, d1 = fx - q0.z;
                float d2 = fx - q1.x, d3 = fx - q1.z;
                float a01 = fminf(fmaf(d0, d0, q0.y), fmaf(d1, d1, q0.w));
                float a23 = fminf(fmaf(d2, d2, q1.y), fmaf(d3, d3, q1.w));
                m1 = fminf(fminf(a01, a23), m1);
            }
        }

        // far-pair skip: both strokes > cut from every lane -> alpha < 2e-9
        const float c0 = w0 + 10.0f;
        const float c1 = w1 + 10.0f;
        if (__all(m0 > c0 * c0) && __all(m1 > c1 * c1)) continue;

        // both alphas compute with ILP; blend strictly s0 then s1
        float al0 = __builtin_amdgcn_rcpf(1.0f + __expf(2.0f * (sqrtf(m0) - w0)));
        float al1 = __builtin_amdgcn_rcpf(1.0f + __expf(2.0f * (sqrtf(m1) - w1)));

        A  *= (1.0f - al0);
        br  = fmaf(al0, col0.x - br, br);
        bg  = fmaf(al0, col0.y - bg, bg);
        bb  = fmaf(al0, col0.z - bb, bb);
        if (has1) {
            A  *= (1.0f - al1);
            br  = fmaf(al1, col1.x - br, br);
            bg  = fmaf(al1, col1.y - bg, bg);
            bb  = fmaf(al1, col1.z - bb, bb);
        }
    }

    // ---- combine: g0 publishes (dedicated buffer), ONE barrier, g1 folds
    if (grp == 0) {
        xfer[px] = make_float4(A, br, bg, bb);
    }
    __syncthreads();
    if (grp == 1) {
        float4 g0 = xfer[px];
        // white canvas: c0 = A0*1 + B0; then c = A1*c0 + B1
        float cr = fmaf(A, g0.x + g0.y, br);
        float cg = fmaf(A, g0.x + g0.z, bg);
        float cb = fmaf(A, g0.x + g0.w, bb);
        const int base = y * CANVAS + px;
        out[0*HW + base] = cr;
        out[1*HW + base] = cg;
        out[2*HW + base] = cb;
    }
}

// ---------------------------------------------------------------------------
// Fallback (ws too small): r17 fused kernel, known-good 17.34us.
// ---------------------------------------------------------------------------
__global__ __launch_bounds__(TPB, 8) void raster_fused_fallback(
    const float* __restrict__ strokes, const float* __restrict__ widths,
    const float* __restrict__ colors, float* __restrict__ out)
{
    __shared__ __align__(16) float2 slist[NSTROKES * LSTRIDE];
    __shared__ float4 scull[NSTROKES];
    __shared__ float4 scol [NSTROKES];
    __shared__ float4 xfer [512];

    const int tid  = threadIdx.x;
    const int wave = tid >> 6;
    const int lane = tid & 63;
    const int px   = tid & 511;
    const int grp  = tid >> 9;
    const int y    = blockIdx.x;
    const float fy = (float)y;

    #pragma unroll
    for (int i = 0; i < SPW; ++i) {
        const int s = wave * SPW + i;
        float4 a = ((const float4*)strokes)[s * 2];
        float4 b = ((const float4*)strokes)[s * 2 + 1];
        const float S = (float)CANVAS;
        float c0x = a.x * S;
        float c1x = 3.0f * (a.z - a.x) * S;
        float c2x = 3.0f * (b.x - 2.0f * a.z + a.x) * S;
        float c3x = (b.z - 3.0f * b.x + 3.0f * a.z - a.x) * S;
        float c0y = a.y * S;
        float c1y = 3.0f * (a.w - a.y) * S;
        float c2y = 3.0f * (b.y - 2.0f * a.w + a.y) * S;
        float c3y = (b.w - 3.0f * b.y + 3.0f * a.w - a.y) * S;

        float w   = widths[s];
        float cut = w + 10.0f;

        float t   = (float)lane * (1.0f / (float)(NSAMP - 1));
        float px_ = fmaf(fmaf(fmaf(c3x, t, c2x), t, c1x), t, c0x);
        float py_ = fmaf(fmaf(fmaf(c3y, t, c2y), t, c1y), t, c0y);

        float dy  = py_ - fy;
        bool keep = (lane < NSAMP) && (fabsf(dy) <= cut);
        unsigned long long mask = __ballot(keep);
        int idx = __popcll(mask & ((1ull << lane) - 1ull));
        if (keep) {
            slist[s * LSTRIDE + idx] = make_float2(px_, dy * dy);
        } else if (lane >= NSAMP) {
            slist[s * LSTRIDE + idx + (lane - NSAMP)] = make_float2(1e15f, 1e15f);
        }

        if (mask) {
            float vmn = keep ? px_ : 1e30f;
            float vmx = keep ? px_ : -1e30f;
            #pragma unroll
            for (int off = 32; off; off >>= 1) {
                vmn = fminf(vmn, __shfl_xor(vmn, off));
                vmx = fmaxf(vmx, __shfl_xor(vmx, off));
            }
            if (lane == 0) {
                scull[s] = make_float4(vmn - cut, vmx + cut, w,
                                       (float)__popcll(mask));
                scol [s] = make_float4(colors[3*s], colors[3*s+1],
                                       colors[3*s+2], 0.0f);
            }
        } else if (lane == 0) {
            scull[s] = make_float4(0.0f, 0.0f, w, 0.0f);
        }
    }
    __syncthreads();

    const float fx      = (float)px;
    const float span_lo = (float)((wave & 7) << 6);
    const float span_hi = span_lo + 63.0f;
    const int   sbase   = grp << 5;

    float4 cbl = scull[sbase + (lane & 31)];
    bool alive = (cbl.w > 0.0f) && (cbl.x <= span_hi) && (cbl.y >= span_lo);
    unsigned int live = (unsigned int)__ballot(alive);

    float A = 1.0f, br = 0.0f, bg = 0.0f, bb = 0.0f;

    while (live) {
        const int s0 = sbase + (__ffs(live) - 1);
        live &= live - 1u;
        const bool has1 = (live != 0u);
        const int s1 = has1 ? (sbase + (__ffs(live) - 1)) : s0;
        if (has1) live &= live - 1u;

        float4 cb0  = scull[s0];
        float4 cb1  = scull[s1];
        float4 col0 = scol [s0];
        float4 col1 = scol [s1];
        const int   kc0 = (int)cb0.w;
        const int   kc1 = has1 ? (int)cb1.w : 0;
        const float w0  = cb0.z;
        const float w1  = cb1.z;

        float m0 = 1e30f, m1 = 1e30f;
        const float4* L0 = (const float4*)(slist + s0 * LSTRIDE);
        const float4* L1 = (const float4*)(slist + s1 * LSTRIDE);

        const int kmax = kc0 > kc1 ? kc0 : kc1;
        for (int j = 0; j < kmax; j += 4) {
            if (j < kc0) {
                float4 q0 = L0[(j >> 1)];
                float4 q1 = L0[(j >> 1) + 1];
                float d0 = fx - q0.x, d1 = fx - q0.z;
                float d2 = fx - q1.x, d3 = fx - q1.z;
                float a01 = fminf(fmaf(d0, d0, q0.y), fmaf(d1, d1, q0.w));
                float a23 = fminf(fmaf(d2, d2, q1.y), fmaf(d3, d3, q1.w));
                m0 = fminf(fminf(a01, a23), m0);
            }
            if (j < kc1) {
                float4 q0 = L1[(j >> 1)];
                float4 q1 = L1[(j >> 1) + 1];
                float d0 = fx - q0.x, d1 = fx - q0.z;
                float d2 = fx - q1.x, d3 = fx - q1.z;
                float a01 = fminf(fmaf(d0, d0, q0.y), fmaf(d1, d1, q0.w));
                float a23 = fminf(fmaf(d2, d2, q1.y), fmaf(d3, d3, q1.w));
                m1 = fminf(fminf(a01, a23), m1);
            }
        }

        float al0 = __builtin_amdgcn_rcpf(1.0f + __expf(2.0f * (sqrtf(m0) - w0)));
        float al1 = __builtin_amdgcn_rcpf(1.0f + __expf(2.0f * (sqrtf(m1) - w1)));

        A  *= (1.0f - al0);
        br  = fmaf(al0, col0.x - br, br);
        bg  = fmaf(al0, col0.y - bg, bg);
        bb  = fmaf(al0, col0.z - bb, bb);
        if (has1) {
            A  *= (1.0f - al1);
            br  = fmaf(al1, col1.x - br, br);
            bg  = fmaf(al1, col1.y - bg, bg);
            bb  = fmaf(al1, col1.z - bb, bb);
        }
    }

    if (grp == 0) {
        xfer[px] = make_float4(A, br, bg, bb);
    }
    __syncthreads();
    if (grp == 1) {
        float4 g0 = xfer[px];
        float cr = fmaf(A, g0.x + g0.y, br);
        float cg = fmaf(A, g0.x + g0.z, bg);
        float cb = fmaf(A, g0.x + g0.w, bb);
        const int base = y * CANVAS + px;
        out[0*HW + base] = cr;
        out[1*HW + base] = cg;
        out[2*HW + base] = cb;
    }
}

extern "C" void kernel_launch(void* const* d_in, const int* in_sizes, int n_in,
                              void* d_out, int out_size, void* d_ws, size_t ws_size,
                              hipStream_t stream) {
    const float* strokes = (const float*)d_in[0];
    const float* widths  = (const float*)d_in[1];
    const float* colors  = (const float*)d_in[2];
    float* out = (float*)d_out;

    if (ws_size >= WS_NEED) {
        float2* ws_pts = (float2*)d_ws;
        sample_kernel<<<dim3((NSTROKES * 64) / 256), dim3(256), 0, stream>>>(
            strokes, ws_pts);
        raster_kernel<<<dim3(CANVAS), dim3(TPB), 0, stream>>>(
            ws_pts, widths, colors, out);
    } else {
        raster_fused_fallback<<<dim3(CANVAS), dim3(TPB), 0, stream>>>(
            strokes, widths, colors, out);
    }
}

// Round 19
// 17.273 us; speedup vs baseline: 1.2959x; 1.2959x over previous
//
#include <hip/hip_runtime.h>

#define NSTROKES 64
#define NSAMP    50
#define CANVAS   512
#define HW       (CANVAS * CANVAS)
#define TPB      1024                  // 512 px x 2 stroke-groups, 16 waves
#define SPW      (NSTROKES / 16)       // 4 strokes per wave (stage A)
#define LSTRIDE  64                    // float2 slots per stroke list

// ---------------------------------------------------------------------------
// r17 kernel, reverted verbatim (best known: 17.34us).
// Single kernel, one block per canvas row.
//  tid = px + 512*grp; grp g composites strokes g*32..g*32+31 (affine map
//  c -> A*c + B), folded via a dedicated xfer buffer (one barrier):
//  c = A1*(A0*white + B0) + B1.
//  stage A: ballot compaction; lists store (px, dy^2) -- dy row-constant,
//  squared once here (removes 8/19 VALU per 4-sample stage-B iteration).
//  stage B: interval cull -> 32-bit live mask; 2 strokes in flight (2x MLP);
//  sentinel-padded 4-wide min loop; blend preserves stroke order bit-exactly.
// ---------------------------------------------------------------------------
__global__ __launch_bounds__(TPB, 8) void raster_fused_kernel(
    const float* __restrict__ strokes,   // (64,4,2)
    const float* __restrict__ widths,    // (64,)
    const float* __restrict__ colors,    // (64,3)
    float* __restrict__ out)             // (1,3,512,512)
{
    __shared__ __align__(16) float2 slist[NSTROKES * LSTRIDE];  // 32 KB
    __shared__ float4 scull[NSTROKES];   // xmin-cut, xmax+cut, w, cnt
    __shared__ float4 scol [NSTROKES];   // r,g,b,pad
    __shared__ float4 xfer [512];        // dedicated combine buffer (8 KB)

    const int tid  = threadIdx.x;
    const int wave = tid >> 6;
    const int lane = tid & 63;
    const int px   = tid & 511;
    const int grp  = tid >> 9;           // 0: strokes 0-31, 1: strokes 32-63
    const int y    = blockIdx.x;
    const float fy = (float)y;

    // ---- stage A: compaction, SPW strokes per wave, lane = sample index
    #pragma unroll
    for (int i = 0; i < SPW; ++i) {
        const int s = wave * SPW + i;        // stroke id 0..63

        float4 a = ((const float4*)strokes)[s * 2];       // p0x,p0y,p1x,p1y
        float4 b = ((const float4*)strokes)[s * 2 + 1];   // p2x,p2y,p3x,p3y
        const float S = (float)CANVAS;
        float c0x = a.x * S;
        float c1x = 3.0f * (a.z - a.x) * S;
        float c2x = 3.0f * (b.x - 2.0f * a.z + a.x) * S;
        float c3x = (b.z - 3.0f * b.x + 3.0f * a.z - a.x) * S;
        float c0y = a.y * S;
        float c1y = 3.0f * (a.w - a.y) * S;
        float c2y = 3.0f * (b.y - 2.0f * a.w + a.y) * S;
        float c3y = (b.w - 3.0f * b.y + 3.0f * a.w - a.y) * S;

        float w   = widths[s];
        float cut = w + 10.0f;               // alpha <= sigmoid(-20) ~ 2e-9 beyond

        float t   = (float)lane * (1.0f / (float)(NSAMP - 1));
        float px_ = fmaf(fmaf(fmaf(c3x, t, c2x), t, c1x), t, c0x);
        float py_ = fmaf(fmaf(fmaf(c3y, t, c2y), t, c1y), t, c0y);

        float dy  = py_ - fy;
        bool keep = (lane < NSAMP) && (fabsf(dy) <= cut);
        unsigned long long mask = __ballot(keep);
        int idx = __popcll(mask & ((1ull << lane) - 1ull));
        if (keep) {
            slist[s * LSTRIDE + idx] = make_float2(px_, dy * dy);  // (px, dy^2)
        } else if (lane >= NSAMP) {
            // lanes 50..63: idx == kc for all -> consecutive sentinel slots
            slist[s * LSTRIDE + idx + (lane - NSAMP)] = make_float2(1e15f, 1e15f);
        }

        if (mask) {
            float vmn = keep ? px_ : 1e30f;
            float vmx = keep ? px_ : -1e30f;
            #pragma unroll
            for (int off = 32; off; off >>= 1) {
                vmn = fminf(vmn, __shfl_xor(vmn, off));
                vmx = fmaxf(vmx, __shfl_xor(vmx, off));
            }
            if (lane == 0) {
                scull[s] = make_float4(vmn - cut, vmx + cut, w,
                                       (float)__popcll(mask));
                scol [s] = make_float4(colors[3*s], colors[3*s+1],
                                       colors[3*s+2], 0.0f);
            }
        } else if (lane == 0) {
            scull[s] = make_float4(0.0f, 0.0f, w, 0.0f);   // cnt=0 -> culled
        }
    }
    __syncthreads();

    // ---- stage B: lane l tests stroke grp*32+(l&31); 32-bit live mask
    const float fx      = (float)px;
    const float span_lo = (float)((wave & 7) << 6);
    const float span_hi = span_lo + 63.0f;
    const int   sbase   = grp << 5;

    float4 cbl = scull[sbase + (lane & 31)];
    bool alive = (cbl.w > 0.0f) && (cbl.x <= span_hi) && (cbl.y >= span_lo);
    unsigned int live = (unsigned int)__ballot(alive);   // low 32 == high 32

    float A = 1.0f, br = 0.0f, bg = 0.0f, bb = 0.0f;

    while (live) {
        // pop up to TWO live strokes (ascending ids: composite order kept)
        const int s0 = sbase + (__ffs(live) - 1);
        live &= live - 1u;
        const bool has1 = (live != 0u);
        const int s1 = has1 ? (sbase + (__ffs(live) - 1)) : s0;
        if (has1) live &= live - 1u;

        // independent LDS reads issue back-to-back (2x MLP)
        float4 cb0  = scull[s0];
        float4 cb1  = scull[s1];
        float4 col0 = scol [s0];
        float4 col1 = scol [s1];
        const int   kc0 = (int)cb0.w;
        const int   kc1 = has1 ? (int)cb1.w : 0;
        const float w0  = cb0.z;
        const float w1  = cb1.z;

        float m0 = 1e30f, m1 = 1e30f;
        const float4* L0 = (const float4*)(slist + s0 * LSTRIDE);
        const float4* L1 = (const float4*)(slist + s1 * LSTRIDE);

        const int kmax = kc0 > kc1 ? kc0 : kc1;
        for (int j = 0; j < kmax; j += 4) {        // sentinel-padded to 4
            if (j < kc0) {                          // wave-uniform branch
                float4 q0 = L0[(j >> 1)];           // (px,dy2, px,dy2)
                float4 q1 = L0[(j >> 1) + 1];
                float d0 = fx - q0.x, d1 = fx - q0.z;
                float d2 = fx - q1.x, d3 = fx - q1.z;
                float a01 = fminf(fmaf(d0, d0, q0.y), fmaf(d1, d1, q0.w));
                float a23 = fminf(fmaf(d2, d2, q1.y), fmaf(d3, d3, q1.w));
                m0 = fminf(fminf(a01, a23), m0);
            }
            if (j < kc1) {                          // wave-uniform branch
                float4 q0 = L1[(j >> 1)];
                float4 q1 = L1[(j >> 1) + 1];
                float d0 = fx - q0.x, d1 = fx - q0.z;
                float d2 = fx - q1.x, d3 = fx - q1.z;
                float a01 = fminf(fmaf(d0, d0, q0.y), fmaf(d1, d1, q0.w));
                float a23 = fminf(fmaf(d2, d2, q1.y), fmaf(d3, d3, q1.w));
                m1 = fminf(fminf(a01, a23), m1);
            }
        }

        // both alphas compute with ILP; blend strictly s0 then s1
        float al0 = __builtin_amdgcn_rcpf(1.0f + __expf(2.0f * (sqrtf(m0) - w0)));
        float al1 = __builtin_amdgcn_rcpf(1.0f + __expf(2.0f * (sqrtf(m1) - w1)));

        A  *= (1.0f - al0);
        br  = fmaf(al0, col0.x - br, br);
        bg  = fmaf(al0, col0.y - bg, bg);
        bb  = fmaf(al0, col0.z - bb, bb);
        if (has1) {
            A  *= (1.0f - al1);
            br  = fmaf(al1, col1.x - br, br);
            bg  = fmaf(al1, col1.y - bg, bg);
            bb  = fmaf(al1, col1.z - bb, bb);
        }
    }

    // ---- combine: g0 publishes immediately (dedicated buffer), ONE barrier
    if (grp == 0) {
        xfer[px] = make_float4(A, br, bg, bb);
    }
    __syncthreads();
    if (grp == 1) {
        float4 g0 = xfer[px];
        // white canvas: c0 = A0*1 + B0; then c = A1*c0 + B1
        float cr = fmaf(A, g0.x + g0.y, br);
        float cg = fmaf(A, g0.x + g0.z, bg);
        float cb = fmaf(A, g0.x + g0.w, bb);
        const int base = y * CANVAS + px;
        out[0*HW + base] = cr;
        out[1*HW + base] = cg;
        out[2*HW + base] = cb;
    }
}

extern "C" void kernel_launch(void* const* d_in, const int* in_sizes, int n_in,
                              void* d_out, int out_size, void* d_ws, size_t ws_size,
                              hipStream_t stream) {
    const float* strokes = (const float*)d_in[0];
    const float* widths  = (const float*)d_in[1];
    const float* colors  = (const float*)d_in[2];
    float* out = (float*)d_out;

    raster_fused_kernel<<<dim3(CANVAS), dim3(TPB), 0, stream>>>(
        strokes, widths, colors, out);
}